// Round 6
// baseline (716.091 us; speedup 1.0000x reference)
//
#include <hip/hip_runtime.h>
#include <math.h>

#define B_SZ 2
#define HH 64
#define WW 64
#define DM 192
#define NS 16
#define RR 12
#define KD 4
#define LL (HH * WW)           // 4096
#define CPROJ (RR + 2 * NS)    // 44
#define CPAD 48
#define NCH 128
#define CH (LL / NCH)          // 32 steps per chunk
#define NBLK (B_SZ * KD * NCH) // 1024 blocks
#define TLP 64                 // l-tile per proj block
#define LOG2E 1.44269504088896340736f
#define LN2F 0.69314718055994530942f

// spatial index (row-major h*W+w) that scan position t of direction k touches
__device__ __forceinline__ int spatial_idx(int k, int t) {
    if (k == 0) return t;
    if (k == 1) return ((t & 63) << 6) | (t >> 6);          // t = w*H + h -> l = h*W + w
    if (k == 2) return LL - 1 - t;
    int tp = LL - 1 - t;
    return ((tp & 63) << 6) | (tp >> 6);
}

__device__ __forceinline__ void compute_dA(float dt, const float* Avl2, bool pw, float* dA) {
    if (pw) {
        float e1 = exp2f(dt * Avl2[0]);
        dA[0] = e1;
        dA[1] = e1 * e1;
        dA[2] = dA[1] * e1;
        dA[3] = dA[1] * dA[1];
        dA[4] = dA[3] * e1;
        dA[5] = dA[3] * dA[1];
        dA[6] = dA[3] * dA[2];
        dA[7] = dA[3] * dA[3];
        dA[8] = dA[7] * e1;
        dA[9] = dA[7] * dA[1];
        dA[10] = dA[7] * dA[2];
        dA[11] = dA[7] * dA[3];
        dA[12] = dA[7] * dA[4];
        dA[13] = dA[7] * dA[5];
        dA[14] = dA[7] * dA[6];
        dA[15] = dA[7] * dA[7];
    } else {
#pragma unroll
        for (int n = 0; n < NS; ++n) dA[n] = exp2f(dt * Avl2[n]);
    }
}

__device__ __forceinline__ void load_params(int kd, const float* __restrict__ dtw,
                                            const float* __restrict__ dtb,
                                            const float* __restrict__ Alogs,
                                            float* Wdt, float& bias, float* Avl2, bool& pw) {
#pragma unroll
    for (int r = 0; r < RR; ++r) Wdt[r] = dtw[(size_t)kd * RR + r];
    bias = dtb[kd];
#pragma unroll
    for (int n = 0; n < NS; ++n) Avl2[n] = -__expf(Alogs[(size_t)kd * NS + n]) * LOG2E;
    bool pws = true;
#pragma unroll
    for (int n = 0; n < NS; ++n)
        pws = pws && (fabsf(Avl2[n] - (float)(n + 1) * Avl2[0]) <= 1e-5f * fabsf(Avl2[n]) + 1e-30f);
    pw = (__all(pws ? 1 : 0) != 0);
}

// stage this block's chunk of xdbl (CH rows x CPAD) into LDS
__device__ __forceinline__ void stage_chunk(int bk, int chunk, int tid,
                                            const float* __restrict__ xdbl, float* xds) {
    float4* dst = (float4*)xds;
    const float4* src = (const float4*)(xdbl + ((size_t)bk * LL + chunk * CH) * CPAD);
    dst[tid] = src[tid];                       // CH*CPAD/4 = 384 float4, 192 threads x 2
    dst[tid + DM] = src[tid + DM];
    __syncthreads();
}

// compute all CH dt values (softplus of projection) from LDS rows — independent iterations
__device__ __forceinline__ void compute_dts(const float* xds, const float* Wdt, float bias,
                                            float* dts) {
#pragma unroll
    for (int tt = 0; tt < CH; ++tt) {
        const float4* r4 = (const float4*)(xds + tt * CPAD);
        float4 a = r4[0], b4 = r4[1], c4 = r4[2];
        // two-way split FMA chains to halve serial latency
        float z0 = fmaf(a.x, Wdt[0], fmaf(a.z, Wdt[2], fmaf(b4.x, Wdt[4],
                   fmaf(b4.z, Wdt[6], fmaf(c4.x, Wdt[8], c4.z * Wdt[10])))));
        float z1 = fmaf(a.y, Wdt[1], fmaf(a.w, Wdt[3], fmaf(b4.y, Wdt[5],
                   fmaf(b4.w, Wdt[7], fmaf(c4.y, Wdt[9], c4.w * Wdt[11])))));
        float z = bias + z0 + z1;
        dts[tt] = (z > 15.f) ? z : __log2f(1.f + exp2f(z * LOG2E)) * LN2F;
    }
}

// ---------------- phase 1: local chunk scan -> carry + aprod ----------------
__global__ __launch_bounds__(192, 3) void scan1_kernel(
    const float* __restrict__ x, const float* __restrict__ xdbl,
    const float* __restrict__ dtw, const float* __restrict__ dtb,
    const float* __restrict__ Alogs,
    float* __restrict__ carry, float* __restrict__ aprod) {
    __shared__ float xds[CH * CPAD];
    const int chunk = blockIdx.x & (NCH - 1);
    const int bk = blockIdx.x >> 7;
    const int k = bk & 3, b = bk >> 2;
    const int d = threadIdx.x;

    stage_chunk(bk, chunk, d, xdbl, xds);

    float Wdt[RR], bias, Avl2[NS];
    bool pw;
    load_params(k * DM + d, dtw, dtb, Alogs, Wdt, bias, Avl2, pw);

    // all x loads issued up-front (independent, coalesced across d)
    const float* xb = x + (size_t)b * LL * DM + d;
    float xv[CH];
#pragma unroll
    for (int tt = 0; tt < CH; ++tt)
        xv[tt] = xb[(size_t)spatial_idx(k, chunk * CH + tt) * DM];

    float dts[CH];
    compute_dts(xds, Wdt, bias, dts);
    float dtsum = 0.f;
#pragma unroll
    for (int tt = 0; tt < CH; ++tt) dtsum += dts[tt];

    float h[NS];
#pragma unroll
    for (int n = 0; n < NS; ++n) h[n] = 0.f;

#pragma unroll
    for (int tt = 0; tt < CH; ++tt) {
        const float4* r4 = (const float4*)(xds + tt * CPAD);
        float4 B0 = r4[3], B1 = r4[4], B2 = r4[5], B3 = r4[6];
        float dA[NS];
        compute_dA(dts[tt], Avl2, pw, dA);
        float dtx = dts[tt] * xv[tt];
        h[0]  = fmaf(dA[0],  h[0],  dtx * B0.x);
        h[1]  = fmaf(dA[1],  h[1],  dtx * B0.y);
        h[2]  = fmaf(dA[2],  h[2],  dtx * B0.z);
        h[3]  = fmaf(dA[3],  h[3],  dtx * B0.w);
        h[4]  = fmaf(dA[4],  h[4],  dtx * B1.x);
        h[5]  = fmaf(dA[5],  h[5],  dtx * B1.y);
        h[6]  = fmaf(dA[6],  h[6],  dtx * B1.z);
        h[7]  = fmaf(dA[7],  h[7],  dtx * B1.w);
        h[8]  = fmaf(dA[8],  h[8],  dtx * B2.x);
        h[9]  = fmaf(dA[9],  h[9],  dtx * B2.y);
        h[10] = fmaf(dA[10], h[10], dtx * B2.z);
        h[11] = fmaf(dA[11], h[11], dtx * B2.w);
        h[12] = fmaf(dA[12], h[12], dtx * B3.x);
        h[13] = fmaf(dA[13], h[13], dtx * B3.y);
        h[14] = fmaf(dA[14], h[14], dtx * B3.z);
        h[15] = fmaf(dA[15], h[15], dtx * B3.w);
    }

    const size_t cbase = ((size_t)blockIdx.x * DM + d) * NS;
#pragma unroll
    for (int n = 0; n < NS; ++n) {
        carry[cbase + n] = h[n];
        aprod[cbase + n] = exp2f(dtsum * Avl2[n]);   // prod of dA == exp(Av * sum dt)
    }
}

// ---------------- phase 2: inter-chunk sequential fixup ----------------
__global__ __launch_bounds__(192) void fix_kernel(float* __restrict__ carry,
                                                  const float* __restrict__ aprod) {
    int idx = blockIdx.x * DM + threadIdx.x;     // 128*192 = 24576 = B*K*D*N
    int n = idx & (NS - 1);
    int dn = idx >> 4;
    int dd = dn % DM;
    int bkc = dn / DM;
    size_t base = ((size_t)bkc * NCH * DM + dd) * NS + n;
    const size_t stride = (size_t)DM * NS;
    float hp = 0.f;
#pragma unroll 4
    for (int c = 0; c < NCH; ++c) {
        size_t off = base + (size_t)c * stride;
        float P = aprod[off];
        float Cr = carry[off];
        carry[off] = hp;                 // state entering chunk c
        hp = fmaf(P, hp, Cr);
    }
}

// ---------------- phase 3: full scan with incoming state, emit y ----------------
__global__ __launch_bounds__(192, 3) void scan3_kernel(
    const float* __restrict__ x, const float* __restrict__ xdbl,
    const float* __restrict__ dtw, const float* __restrict__ dtb,
    const float* __restrict__ Alogs, const float* __restrict__ Ds,
    const float* __restrict__ carry, float* __restrict__ ybuf4) {
    __shared__ float xds[CH * CPAD];
    const int chunk = blockIdx.x & (NCH - 1);
    const int bk = blockIdx.x >> 7;
    const int k = bk & 3, b = bk >> 2;
    const int d = threadIdx.x;

    stage_chunk(bk, chunk, d, xdbl, xds);

    float Wdt[RR], bias, Avl2[NS];
    bool pw;
    load_params(k * DM + d, dtw, dtb, Alogs, Wdt, bias, Avl2, pw);
    const float Dval = Ds[k * DM + d];

    const float* xb = x + (size_t)b * LL * DM + d;
    float xv[CH];
#pragma unroll
    for (int tt = 0; tt < CH; ++tt)
        xv[tt] = xb[(size_t)spatial_idx(k, chunk * CH + tt) * DM];

    float dts[CH];
    compute_dts(xds, Wdt, bias, dts);

    const size_t cbase = ((size_t)blockIdx.x * DM + d) * NS;
    float h[NS];
#pragma unroll
    for (int n = 0; n < NS; ++n) h[n] = carry[cbase + n];

    float* yk = ybuf4 + (size_t)k * ((size_t)B_SZ * LL * DM) + (size_t)b * LL * DM + d;

#pragma unroll
    for (int tt = 0; tt < CH; ++tt) {
        const float4* r4 = (const float4*)(xds + tt * CPAD);
        float4 B0 = r4[3], B1 = r4[4], B2 = r4[5], B3 = r4[6];
        float4 C0 = r4[7], C1 = r4[8], C2 = r4[9], C3 = r4[10];
        float dA[NS];
        compute_dA(dts[tt], Avl2, pw, dA);
        float dtx = dts[tt] * xv[tt];
        float y0, y1, y2, y3;
        h[0]  = fmaf(dA[0],  h[0],  dtx * B0.x);  y0 = h[0] * C0.x;
        h[1]  = fmaf(dA[1],  h[1],  dtx * B0.y);  y1 = h[1] * C0.y;
        h[2]  = fmaf(dA[2],  h[2],  dtx * B0.z);  y2 = h[2] * C0.z;
        h[3]  = fmaf(dA[3],  h[3],  dtx * B0.w);  y3 = h[3] * C0.w;
        h[4]  = fmaf(dA[4],  h[4],  dtx * B1.x);  y0 = fmaf(h[4],  C1.x, y0);
        h[5]  = fmaf(dA[5],  h[5],  dtx * B1.y);  y1 = fmaf(h[5],  C1.y, y1);
        h[6]  = fmaf(dA[6],  h[6],  dtx * B1.z);  y2 = fmaf(h[6],  C1.z, y2);
        h[7]  = fmaf(dA[7],  h[7],  dtx * B1.w);  y3 = fmaf(h[7],  C1.w, y3);
        h[8]  = fmaf(dA[8],  h[8],  dtx * B2.x);  y0 = fmaf(h[8],  C2.x, y0);
        h[9]  = fmaf(dA[9],  h[9],  dtx * B2.y);  y1 = fmaf(h[9],  C2.y, y1);
        h[10] = fmaf(dA[10], h[10], dtx * B2.z);  y2 = fmaf(h[10], C2.z, y2);
        h[11] = fmaf(dA[11], h[11], dtx * B2.w);  y3 = fmaf(h[11], C2.w, y3);
        h[12] = fmaf(dA[12], h[12], dtx * B3.x);  y0 = fmaf(h[12], C3.x, y0);
        h[13] = fmaf(dA[13], h[13], dtx * B3.y);  y1 = fmaf(h[13], C3.y, y1);
        h[14] = fmaf(dA[14], h[14], dtx * B3.z);  y2 = fmaf(h[14], C3.z, y2);
        h[15] = fmaf(dA[15], h[15], dtx * B3.w);  y3 = fmaf(h[15], C3.w, y3);
        int s = spatial_idx(k, chunk * CH + tt);
        yk[(size_t)s * DM] = (y0 + y1) + (y2 + y3) + Dval * xv[tt];
    }
}

// ---------------- projection: xdbl[bk][l][c] = sum_d xs[b,k,d,l] * W[k,c,d] ----------------
__global__ __launch_bounds__(256) void proj_kernel(const float* __restrict__ x,
                                                   const float* __restrict__ xpw,
                                                   float* __restrict__ xdbl) {
    int blk = blockIdx.x;                    // B*K*(L/TLP) = 512
    int ltile = blk % (LL / TLP);
    int bk = blk / (LL / TLP);
    int k = bk & 3;
    int b = bk >> 2;
    int l0 = ltile * TLP;

    __shared__ float xt[DM * (TLP + 1)];     // transposed tile, stride 65 -> conflict-free reads

    {
        int li = threadIdx.x >> 2;
        int d0 = (threadIdx.x & 3) * 48;
        int s = spatial_idx(k, l0 + li);
        const float4* xr = (const float4*)(x + ((size_t)b * LL + s) * DM + d0);
#pragma unroll
        for (int q = 0; q < 12; ++q) {
            float4 v = xr[q];
            int d = d0 + q * 4;
            xt[(d + 0) * (TLP + 1) + li] = v.x;
            xt[(d + 1) * (TLP + 1) + li] = v.y;
            xt[(d + 2) * (TLP + 1) + li] = v.z;
            xt[(d + 3) * (TLP + 1) + li] = v.w;
        }
    }
    __syncthreads();

    int lane = threadIdx.x & 63;
    int wv = threadIdx.x >> 6;               // 0..3
    int c0 = __builtin_amdgcn_readfirstlane(wv * 11);
    const float* wk = xpw + (size_t)k * CPROJ * DM;

    float acc[11];
#pragma unroll
    for (int ci = 0; ci < 11; ++ci) acc[ci] = 0.f;

    for (int d = 0; d < DM; ++d) {
        float xv = xt[d * (TLP + 1) + lane];
#pragma unroll
        for (int ci = 0; ci < 11; ++ci)
            acc[ci] = fmaf(xv, wk[(size_t)(c0 + ci) * DM + d], acc[ci]);
    }
    float* orow = xdbl + ((size_t)bk * LL + l0 + lane) * CPAD;
#pragma unroll
    for (int ci = 0; ci < 11; ++ci) orow[c0 + ci] = acc[ci];
}

// ---------------- LayerNorm over D=192 with 4-direction merge, wave per row ----------------
__global__ __launch_bounds__(256) void ln_kernel(const float* __restrict__ ybuf,
                                                 const float* __restrict__ lnw,
                                                 const float* __restrict__ lnb,
                                                 float* __restrict__ out) {
    const size_t SEG = (size_t)B_SZ * LL * DM;
    int row = blockIdx.x * 4 + (threadIdx.x >> 6);   // B*L rows
    int lane = threadIdx.x & 63;
    const float* yr = ybuf + (size_t)row * DM;
    float v0 = 0.f, v1 = 0.f, v2 = 0.f;
#pragma unroll
    for (int kq = 0; kq < KD; ++kq) {
        const float* p = yr + kq * SEG;
        v0 += p[lane];
        v1 += p[lane + 64];
        v2 += p[lane + 128];
    }
    float s = v0 + v1 + v2;
    float sq = v0 * v0 + v1 * v1 + v2 * v2;
#pragma unroll
    for (int off = 32; off >= 1; off >>= 1) {
        s += __shfl_xor(s, off, 64);
        sq += __shfl_xor(sq, off, 64);
    }
    float mu = s * (1.f / DM);
    float var = sq * (1.f / DM) - mu * mu;
    float inv = rsqrtf(var + 1e-5f);
    float* orow = out + (size_t)row * DM;
    orow[lane]       = (v0 - mu) * inv * lnw[lane]       + lnb[lane];
    orow[lane + 64]  = (v1 - mu) * inv * lnw[lane + 64]  + lnb[lane + 64];
    orow[lane + 128] = (v2 - mu) * inv * lnw[lane + 128] + lnb[lane + 128];
}

extern "C" void kernel_launch(void* const* d_in, const int* in_sizes, int n_in,
                              void* d_out, int out_size, void* d_ws, size_t ws_size,
                              hipStream_t stream) {
    const float* x    = (const float*)d_in[0];
    const float* xpw  = (const float*)d_in[1];
    const float* dtw  = (const float*)d_in[2];
    const float* dtb  = (const float*)d_in[3];
    const float* Alog = (const float*)d_in[4];
    const float* Ds   = (const float*)d_in[5];
    const float* lnw  = (const float*)d_in[6];
    const float* lnb  = (const float*)d_in[7];
    float* out = (float*)d_out;

    const size_t F_XD = (size_t)B_SZ * KD * LL * CPAD;       // 1,572,864 floats (6.3 MB)
    const size_t F_CR = (size_t)B_SZ * KD * NCH * DM * NS;   // 3,145,728 floats (12.6 MB)
    const size_t F_YB = (size_t)B_SZ * LL * DM;              // 1,572,864 floats (6.3 MB)

    float* ws    = (float*)d_ws;
    float* xdbl  = ws;
    float* carry = xdbl + F_XD;
    float* aprod = carry + F_CR;
    float* ybuf4 = aprod + F_CR;                             // 4 segments, 25.2 MB

    proj_kernel<<<B_SZ * KD * (LL / TLP), 256, 0, stream>>>(x, xpw, xdbl);
    scan1_kernel<<<NBLK, DM, 0, stream>>>(x, xdbl, dtw, dtb, Alog, carry, aprod);
    fix_kernel<<<128, DM, 0, stream>>>(carry, aprod);
    scan3_kernel<<<NBLK, DM, 0, stream>>>(x, xdbl, dtw, dtb, Alog, Ds, carry, ybuf4);
    ln_kernel<<<(B_SZ * LL) / 4, 256, 0, stream>>>(ybuf4, lnw, lnb, out);
}

// Round 7
// 115.066 us; speedup vs baseline: 6.2233x; 6.2233x over previous
//
#include <hip/hip_runtime.h>
#include <math.h>

#define B_SZ 2
#define HH 64
#define WW 64
#define DM 192
#define NS 16
#define RR 12
#define KD 4
#define LL (HH * WW)           // 4096
#define CPROJ (RR + 2 * NS)    // 44
#define CPAD 48
#define NCH 128
#define CH (LL / NCH)          // 32 steps per chunk
#define NBLK (B_SZ * KD * NCH) // 1024 blocks
#define TLP 64                 // l-tile per proj block
#define LOG2E 1.44269504088896340736f
#define LN2F 0.69314718055994530942f

// component i (compile-time after unroll) of a float4 register array
#define RQF(arr, i) (((i) & 3) == 0 ? arr[(i) >> 2].x : ((i) & 3) == 1 ? arr[(i) >> 2].y \
                     : ((i) & 3) == 2 ? arr[(i) >> 2].z : arr[(i) >> 2].w)

// spatial index (row-major h*W+w) that scan position t of direction k touches
__device__ __forceinline__ int spatial_idx(int k, int t) {
    if (k == 0) return t;
    if (k == 1) return ((t & 63) << 6) | (t >> 6);          // t = w*H + h -> l = h*W + w
    if (k == 2) return LL - 1 - t;
    int tp = LL - 1 - t;
    return ((tp & 63) << 6) | (tp >> 6);
}

__device__ __forceinline__ void compute_dA(float dt, const float* Avl2, bool pw, float* dA) {
    if (pw) {
        float e1 = exp2f(dt * Avl2[0]);
        dA[0] = e1;
        dA[1] = e1 * e1;
        dA[2] = dA[1] * e1;
        dA[3] = dA[1] * dA[1];
        dA[4] = dA[3] * e1;
        dA[5] = dA[3] * dA[1];
        dA[6] = dA[3] * dA[2];
        dA[7] = dA[3] * dA[3];
        dA[8] = dA[7] * e1;
        dA[9] = dA[7] * dA[1];
        dA[10] = dA[7] * dA[2];
        dA[11] = dA[7] * dA[3];
        dA[12] = dA[7] * dA[4];
        dA[13] = dA[7] * dA[5];
        dA[14] = dA[7] * dA[6];
        dA[15] = dA[7] * dA[7];
    } else {
#pragma unroll
        for (int n = 0; n < NS; ++n) dA[n] = exp2f(dt * Avl2[n]);
    }
}

__device__ __forceinline__ void load_params(int kd, const float* __restrict__ dtw,
                                            const float* __restrict__ dtb,
                                            const float* __restrict__ Alogs,
                                            float* Wdt, float& bias, float* Avl2, bool& pw) {
#pragma unroll
    for (int r = 0; r < RR; ++r) Wdt[r] = dtw[(size_t)kd * RR + r];
    bias = dtb[kd];
#pragma unroll
    for (int n = 0; n < NS; ++n) Avl2[n] = -__expf(Alogs[(size_t)kd * NS + n]) * LOG2E;
    bool pws = true;
#pragma unroll
    for (int n = 0; n < NS; ++n)
        pws = pws && (fabsf(Avl2[n] - (float)(n + 1) * Avl2[0]) <= 1e-5f * fabsf(Avl2[n]) + 1e-30f);
    pw = (__all(pws ? 1 : 0) != 0);
}

// ---------------- chunked selective scan, phases 1 (carries) and 3 (emit y) ----------------
// All per-step inputs (xdbl rows AND x values) staged in LDS up front: the recurrence
// loop touches only LDS — no global-load latency inside the serial chain.
template <int PHASE>
__global__ __launch_bounds__(192) void scan_kernel(
    const float* __restrict__ x, const float* __restrict__ xdbl,
    const float* __restrict__ dtw, const float* __restrict__ dtb,
    const float* __restrict__ Alogs, const float* __restrict__ Ds,
    float* __restrict__ carry, float* __restrict__ aprod, float* __restrict__ ybuf4) {
    const int chunk = blockIdx.x & (NCH - 1);
    const int bk = blockIdx.x >> 7;
    const int k = bk & 3, b = bk >> 2;
    const int d = threadIdx.x;                 // 0..191
    const int kd = k * DM + d;
    const int tbase = chunk * CH;

    __shared__ float xds[CH * CPAD];           // 6 KB: xdbl chunk
    __shared__ float xs[CH * DM];              // 24 KB: x rows in scan order

    // stage xdbl chunk (384 float4, 2 per thread)
    {
        float4* dst = (float4*)xds;
        const float4* src = (const float4*)(xdbl + ((size_t)bk * LL + tbase) * CPAD);
        dst[threadIdx.x] = src[threadIdx.x];
        dst[threadIdx.x + DM] = src[threadIdx.x + DM];
    }
    // stage x rows: 32 rows x 48 float4, 48 threads per row, 4 rows per pass
    {
        const float* xbase = x + (size_t)b * LL * DM;
        float4* dst = (float4*)xs;
        int rr = threadIdx.x / 48;
        int cc = threadIdx.x - rr * 48;
#pragma unroll
        for (int pass = 0; pass < 8; ++pass) {
            int r = rr + pass * 4;
            int s = spatial_idx(k, tbase + r);
            dst[r * 48 + cc] = ((const float4*)(xbase + (size_t)s * DM))[cc];
        }
    }
    __syncthreads();

    float Wdt[RR], bias, Avl2[NS];
    bool pw;
    load_params(kd, dtw, dtb, Alogs, Wdt, bias, Avl2, pw);
    const float Dval = (PHASE == 3) ? Ds[kd] : 0.f;

    const size_t cbase = ((size_t)blockIdx.x * DM + d) * NS;
    float h[NS];
    if (PHASE == 1) {
#pragma unroll
        for (int n = 0; n < NS; ++n) h[n] = 0.f;
    } else {
#pragma unroll
        for (int n = 0; n < NS; ++n) h[n] = carry[cbase + n];   // h_in from fix_kernel
    }
    float dtsum = 0.f;
    float* yk = ybuf4 + (size_t)k * ((size_t)B_SZ * LL * DM) + (size_t)b * LL * DM + d;

#pragma unroll 4
    for (int tt = 0; tt < CH; ++tt) {
        const float4* r4 = (const float4*)(xds + tt * CPAD);
        float4 rq[11];
#pragma unroll
        for (int q = 0; q < (PHASE == 1 ? 7 : 11); ++q) rq[q] = r4[q];
        // dt projection, two-way split FMA chains
        float z0 = fmaf(RQF(rq, 0), Wdt[0], fmaf(RQF(rq, 2), Wdt[2], fmaf(RQF(rq, 4), Wdt[4],
                   fmaf(RQF(rq, 6), Wdt[6], fmaf(RQF(rq, 8), Wdt[8], RQF(rq, 10) * Wdt[10])))));
        float z1 = fmaf(RQF(rq, 1), Wdt[1], fmaf(RQF(rq, 3), Wdt[3], fmaf(RQF(rq, 5), Wdt[5],
                   fmaf(RQF(rq, 7), Wdt[7], fmaf(RQF(rq, 9), Wdt[9], RQF(rq, 11) * Wdt[11])))));
        float z = bias + z0 + z1;
        float dt = (z > 15.f) ? z : __log2f(1.f + exp2f(z * LOG2E)) * LN2F;
        float xv = xs[tt * DM + d];
        float dtx = dt * xv;
        float dA[NS];
        compute_dA(dt, Avl2, pw, dA);
        if (PHASE == 1) {
            dtsum += dt;
#pragma unroll
            for (int n = 0; n < NS; ++n)
                h[n] = fmaf(dA[n], h[n], dtx * RQF(rq, RR + n));
        } else {
            float y0 = 0.f, y1 = 0.f, y2 = 0.f, y3 = 0.f;
            h[0]  = fmaf(dA[0],  h[0],  dtx * RQF(rq, 12));  y0 = fmaf(h[0],  RQF(rq, 28), y0);
            h[1]  = fmaf(dA[1],  h[1],  dtx * RQF(rq, 13));  y1 = fmaf(h[1],  RQF(rq, 29), y1);
            h[2]  = fmaf(dA[2],  h[2],  dtx * RQF(rq, 14));  y2 = fmaf(h[2],  RQF(rq, 30), y2);
            h[3]  = fmaf(dA[3],  h[3],  dtx * RQF(rq, 15));  y3 = fmaf(h[3],  RQF(rq, 31), y3);
            h[4]  = fmaf(dA[4],  h[4],  dtx * RQF(rq, 16));  y0 = fmaf(h[4],  RQF(rq, 32), y0);
            h[5]  = fmaf(dA[5],  h[5],  dtx * RQF(rq, 17));  y1 = fmaf(h[5],  RQF(rq, 33), y1);
            h[6]  = fmaf(dA[6],  h[6],  dtx * RQF(rq, 18));  y2 = fmaf(h[6],  RQF(rq, 34), y2);
            h[7]  = fmaf(dA[7],  h[7],  dtx * RQF(rq, 19));  y3 = fmaf(h[7],  RQF(rq, 35), y3);
            h[8]  = fmaf(dA[8],  h[8],  dtx * RQF(rq, 20));  y0 = fmaf(h[8],  RQF(rq, 36), y0);
            h[9]  = fmaf(dA[9],  h[9],  dtx * RQF(rq, 21));  y1 = fmaf(h[9],  RQF(rq, 37), y1);
            h[10] = fmaf(dA[10], h[10], dtx * RQF(rq, 22));  y2 = fmaf(h[10], RQF(rq, 38), y2);
            h[11] = fmaf(dA[11], h[11], dtx * RQF(rq, 23));  y3 = fmaf(h[11], RQF(rq, 39), y3);
            h[12] = fmaf(dA[12], h[12], dtx * RQF(rq, 24));  y0 = fmaf(h[12], RQF(rq, 40), y0);
            h[13] = fmaf(dA[13], h[13], dtx * RQF(rq, 25));  y1 = fmaf(h[13], RQF(rq, 41), y1);
            h[14] = fmaf(dA[14], h[14], dtx * RQF(rq, 26));  y2 = fmaf(h[14], RQF(rq, 42), y2);
            h[15] = fmaf(dA[15], h[15], dtx * RQF(rq, 27));  y3 = fmaf(h[15], RQF(rq, 43), y3);
            int s = spatial_idx(k, tbase + tt);
            yk[(size_t)s * DM] = (y0 + y1) + (y2 + y3) + Dval * xv;
        }
    }

    if (PHASE == 1) {
#pragma unroll
        for (int n = 0; n < NS; ++n) {
            carry[cbase + n] = h[n];
            aprod[cbase + n] = exp2f(dtsum * Avl2[n]);   // prod of dA == exp(Av * sum dt)
        }
    }
}

// ---------------- phase 2: inter-chunk sequential fixup ----------------
__global__ __launch_bounds__(192) void fix_kernel(float* __restrict__ carry,
                                                  const float* __restrict__ aprod) {
    int idx = blockIdx.x * DM + threadIdx.x;     // 128*192 = 24576 = B*K*D*N
    int n = idx & (NS - 1);
    int dn = idx >> 4;
    int dd = dn % DM;
    int bkc = dn / DM;
    size_t base = ((size_t)bkc * NCH * DM + dd) * NS + n;
    const size_t stride = (size_t)DM * NS;
    float hp = 0.f;
#pragma unroll 4
    for (int c = 0; c < NCH; ++c) {
        size_t off = base + (size_t)c * stride;
        float P = aprod[off];
        float Cr = carry[off];
        carry[off] = hp;                 // state entering chunk c
        hp = fmaf(P, hp, Cr);
    }
}

// ---------------- projection: xdbl[bk][l][c] = sum_d xs[b,k,d,l] * W[k,c,d] ----------------
__global__ __launch_bounds__(256) void proj_kernel(const float* __restrict__ x,
                                                   const float* __restrict__ xpw,
                                                   float* __restrict__ xdbl) {
    int blk = blockIdx.x;                    // B*K*(L/TLP) = 512
    int ltile = blk % (LL / TLP);
    int bk = blk / (LL / TLP);
    int k = bk & 3;
    int b = bk >> 2;
    int l0 = ltile * TLP;

    __shared__ float xt[DM * (TLP + 1)];     // transposed tile, stride 65 -> conflict-free reads

    {
        int li = threadIdx.x >> 2;
        int d0 = (threadIdx.x & 3) * 48;
        int s = spatial_idx(k, l0 + li);
        const float4* xr = (const float4*)(x + ((size_t)b * LL + s) * DM + d0);
#pragma unroll
        for (int q = 0; q < 12; ++q) {
            float4 v = xr[q];
            int d = d0 + q * 4;
            xt[(d + 0) * (TLP + 1) + li] = v.x;
            xt[(d + 1) * (TLP + 1) + li] = v.y;
            xt[(d + 2) * (TLP + 1) + li] = v.z;
            xt[(d + 3) * (TLP + 1) + li] = v.w;
        }
    }
    __syncthreads();

    int lane = threadIdx.x & 63;
    int wv = threadIdx.x >> 6;               // 0..3
    int c0 = __builtin_amdgcn_readfirstlane(wv * 11);
    const float* wk = xpw + (size_t)k * CPROJ * DM;

    float acc[11];
#pragma unroll
    for (int ci = 0; ci < 11; ++ci) acc[ci] = 0.f;

    for (int d = 0; d < DM; ++d) {
        float xv = xt[d * (TLP + 1) + lane];
#pragma unroll
        for (int ci = 0; ci < 11; ++ci)
            acc[ci] = fmaf(xv, wk[(size_t)(c0 + ci) * DM + d], acc[ci]);
    }
    float* orow = xdbl + ((size_t)bk * LL + l0 + lane) * CPAD;
#pragma unroll
    for (int ci = 0; ci < 11; ++ci) orow[c0 + ci] = acc[ci];
}

// ---------------- LayerNorm over D=192 with 4-direction merge, wave per row ----------------
__global__ __launch_bounds__(256) void ln_kernel(const float* __restrict__ ybuf,
                                                 const float* __restrict__ lnw,
                                                 const float* __restrict__ lnb,
                                                 float* __restrict__ out) {
    const size_t SEG = (size_t)B_SZ * LL * DM;
    int row = blockIdx.x * 4 + (threadIdx.x >> 6);   // B*L rows
    int lane = threadIdx.x & 63;
    const float* yr = ybuf + (size_t)row * DM;
    float v0 = 0.f, v1 = 0.f, v2 = 0.f;
#pragma unroll
    for (int kq = 0; kq < KD; ++kq) {
        const float* p = yr + kq * SEG;
        v0 += p[lane];
        v1 += p[lane + 64];
        v2 += p[lane + 128];
    }
    float s = v0 + v1 + v2;
    float sq = v0 * v0 + v1 * v1 + v2 * v2;
#pragma unroll
    for (int off = 32; off >= 1; off >>= 1) {
        s += __shfl_xor(s, off, 64);
        sq += __shfl_xor(sq, off, 64);
    }
    float mu = s * (1.f / DM);
    float var = sq * (1.f / DM) - mu * mu;
    float inv = rsqrtf(var + 1e-5f);
    float* orow = out + (size_t)row * DM;
    orow[lane]       = (v0 - mu) * inv * lnw[lane]       + lnb[lane];
    orow[lane + 64]  = (v1 - mu) * inv * lnw[lane + 64]  + lnb[lane + 64];
    orow[lane + 128] = (v2 - mu) * inv * lnw[lane + 128] + lnb[lane + 128];
}

extern "C" void kernel_launch(void* const* d_in, const int* in_sizes, int n_in,
                              void* d_out, int out_size, void* d_ws, size_t ws_size,
                              hipStream_t stream) {
    const float* x    = (const float*)d_in[0];
    const float* xpw  = (const float*)d_in[1];
    const float* dtw  = (const float*)d_in[2];
    const float* dtb  = (const float*)d_in[3];
    const float* Alog = (const float*)d_in[4];
    const float* Ds   = (const float*)d_in[5];
    const float* lnw  = (const float*)d_in[6];
    const float* lnb  = (const float*)d_in[7];
    float* out = (float*)d_out;

    const size_t F_XD = (size_t)B_SZ * KD * LL * CPAD;       // 1,572,864 floats (6.3 MB)
    const size_t F_CR = (size_t)B_SZ * KD * NCH * DM * NS;   // 3,145,728 floats (12.6 MB)

    float* ws    = (float*)d_ws;
    float* xdbl  = ws;
    float* carry = xdbl + F_XD;
    float* aprod = carry + F_CR;
    float* ybuf4 = aprod + F_CR;                             // 4 segments, 25.2 MB

    proj_kernel<<<B_SZ * KD * (LL / TLP), 256, 0, stream>>>(x, xpw, xdbl);
    scan_kernel<1><<<NBLK, DM, 0, stream>>>(x, xdbl, dtw, dtb, Alog, Ds, carry, aprod, ybuf4);
    fix_kernel<<<128, DM, 0, stream>>>(carry, aprod);
    scan_kernel<3><<<NBLK, DM, 0, stream>>>(x, xdbl, dtw, dtb, Alog, Ds, carry, aprod, ybuf4);
    ln_kernel<<<(B_SZ * LL) / 4, 256, 0, stream>>>(ybuf4, lnw, lnb, out);
}